// Round 1
// baseline (786.718 us; speedup 1.0000x reference)
//
#include <hip/hip_runtime.h>

#define NN 50000
#define EE 800000
#define ATTN_BLOCKS 768          // 3 blocks/CU x 256 CUs
#define ATTN_WAVES (ATTN_BLOCKS * 4)

using bf16x8 = __attribute__((ext_vector_type(8))) short;
using f32x4  = __attribute__((ext_vector_type(4))) float;
using u16x8  = __attribute__((ext_vector_type(8))) unsigned short;

__device__ __forceinline__ float b2f(unsigned short u) {
    return __uint_as_float(((unsigned)u) << 16);
}
__device__ __forceinline__ unsigned short f2b(float f) {
    unsigned u = __float_as_uint(f);
    u += 0x7FFF + ((u >> 16) & 1);   // round-to-nearest-even
    return (unsigned short)(u >> 16);
}

// ---------------------------------------------------------------------------
// prep: W_q|W_k|W_v|W_skip (fp32) -> Wt[512][128] bf16 (Wt[n][k] = W[k][n]),
//       W_e (fp32) -> Wet[128][96] bf16, and clear deg[]
// ---------------------------------------------------------------------------
__global__ void prep_kernel(const float* __restrict__ Wq,
                            const float* __restrict__ Wk,
                            const float* __restrict__ Wv,
                            const float* __restrict__ Ws,
                            const float* __restrict__ We,
                            unsigned short* __restrict__ Wt,
                            unsigned short* __restrict__ Wet,
                            int* __restrict__ deg) {
    int i = blockIdx.x * 256 + threadIdx.x;
    if (i < 512 * 128) {
        int n = i >> 7, k = i & 127;
        const float* W = (n < 128) ? Wq : (n < 256) ? Wk : (n < 384) ? Wv : Ws;
        Wt[i] = f2b(W[k * 128 + (n & 127)]);
    } else if (i < 512 * 128 + 128 * 96) {
        int j = i - 512 * 128;
        int n = j / 96, k = j - n * 96;
        Wet[j] = f2b(We[k * 128 + n]);
    }
    if (i < NN) deg[i] = 0;
}

// ---------------------------------------------------------------------------
// node projections: X[N,128]fp32 x Wt[512,128]bf16 -> Q,K,V,Skip (bf16)
// ---------------------------------------------------------------------------
__global__ __launch_bounds__(256) void node_gemm(
        const float* __restrict__ X, const unsigned short* __restrict__ Wt,
        const float* __restrict__ bq, const float* __restrict__ bk,
        const float* __restrict__ bv, const float* __restrict__ bs,
        unsigned short* __restrict__ Qb, unsigned short* __restrict__ Kb,
        unsigned short* __restrict__ Vb, unsigned short* __restrict__ Sb) {
    __shared__ unsigned short Al[64][136];   // pitch 136: 2-way bank aliasing (free)
    __shared__ unsigned short Bl[64][136];
    const int tid = threadIdx.x;
    const int m0 = blockIdx.x * 64;
    const int row = tid >> 2, seg = tid & 3;
    {
        int gr = m0 + row;
        float xv[32];
#pragma unroll
        for (int i = 0; i < 32; i++) xv[i] = 0.f;
        if (gr < NN) {
            const float4* s = (const float4*)(X + (size_t)gr * 128 + seg * 32);
#pragma unroll
            for (int i = 0; i < 8; i++) *(float4*)&xv[i * 4] = s[i];
        }
#pragma unroll
        for (int c = 0; c < 4; c++) {
            u16x8 h;
#pragma unroll
            for (int j = 0; j < 8; j++) h[j] = f2b(xv[c * 8 + j]);
            *(u16x8*)&Al[row][seg * 32 + c * 8] = h;
        }
    }
    const int wave = tid >> 6, lane = tid & 63, quad = lane >> 4, l16 = lane & 15;
    for (int n0t = 0; n0t < 8; n0t++) {
        __syncthreads();   // prior MFMA LDS reads done (and Al staged, iter 0)
        {
            const uint4* sb = (const uint4*)(Wt + (size_t)(n0t * 64 + row) * 128 + seg * 32);
            uint4 b0 = sb[0], b1 = sb[1], b2 = sb[2], b3 = sb[3];
            uint4* db = (uint4*)&Bl[row][seg * 32];
            db[0] = b0; db[1] = b1; db[2] = b2; db[3] = b3;
        }
        __syncthreads();
        f32x4 acc[4] = {{0.f,0.f,0.f,0.f},{0.f,0.f,0.f,0.f},{0.f,0.f,0.f,0.f},{0.f,0.f,0.f,0.f}};
#pragma unroll
        for (int kk = 0; kk < 4; kk++) {
            bf16x8 af = *(const bf16x8*)&Al[wave * 16 + l16][kk * 32 + quad * 8];
#pragma unroll
            for (int nf = 0; nf < 4; nf++) {
                bf16x8 bg = *(const bf16x8*)&Bl[nf * 16 + l16][kk * 32 + quad * 8];
                acc[nf] = __builtin_amdgcn_mfma_f32_16x16x32_bf16(af, bg, acc[nf], 0, 0, 0);
            }
        }
        const int sel = n0t >> 1;
        const float* bias    = sel == 0 ? bq : sel == 1 ? bk : sel == 2 ? bv : bs;
        unsigned short* outp = sel == 0 ? Qb : sel == 1 ? Kb : sel == 2 ? Vb : Sb;
#pragma unroll
        for (int nf = 0; nf < 4; nf++) {
            int col = (n0t & 1) * 64 + nf * 16 + l16;
            float bvl = bias[col];
#pragma unroll
            for (int r = 0; r < 4; r++) {
                int orow = m0 + wave * 16 + quad * 4 + r;   // C/D: row = quad*4+reg
                if (orow < NN) outp[(size_t)orow * 128 + col] = f2b(acc[nf][r] + bvl);
            }
        }
    }
}

// ---------------------------------------------------------------------------
// CSR build: deg histogram -> hierarchical exclusive scan -> scatter edge ids
// ---------------------------------------------------------------------------
__global__ void deg_kernel(const int* __restrict__ ei, int* __restrict__ deg) {
    int e = blockIdx.x * 256 + threadIdx.x;
    if (e < EE) atomicAdd(&deg[ei[EE + e]], 1);
}

#define SCAN_BLKS 196   // 196*256 = 50176 >= NN

__global__ __launch_bounds__(256) void scan1_kernel(const int* __restrict__ deg,
                                                    int* __restrict__ off,
                                                    int* __restrict__ bsum) {
    __shared__ int sm[256];
    int tid = threadIdx.x;
    int i = blockIdx.x * 256 + tid;
    int v = (i < NN) ? deg[i] : 0;
    sm[tid] = v;
    __syncthreads();
    for (int d = 1; d < 256; d <<= 1) {
        int t = (tid >= d) ? sm[tid - d] : 0;
        __syncthreads();
        sm[tid] += t;
        __syncthreads();
    }
    if (i < NN) off[i] = sm[tid] - v;           // block-local exclusive
    if (tid == 255) bsum[blockIdx.x] = sm[255]; // block total
}

__global__ __launch_bounds__(256) void scan2_kernel(int* __restrict__ bsum,
                                                    int* __restrict__ bpre,
                                                    int* __restrict__ off) {
    __shared__ int sm[256];
    int tid = threadIdx.x;
    int v = (tid < SCAN_BLKS) ? bsum[tid] : 0;
    sm[tid] = v;
    __syncthreads();
    for (int d = 1; d < 256; d <<= 1) {
        int t = (tid >= d) ? sm[tid - d] : 0;
        __syncthreads();
        sm[tid] += t;
        __syncthreads();
    }
    if (tid < SCAN_BLKS) bpre[tid] = sm[tid] - v;
    if (tid == 255) off[NN] = sm[255];          // = EE
}

__global__ __launch_bounds__(256) void scan3_kernel(int* __restrict__ off,
                                                    const int* __restrict__ bpre,
                                                    int* __restrict__ cur) {
    int i = blockIdx.x * 256 + threadIdx.x;
    if (i < NN) {
        int o = off[i] + bpre[blockIdx.x];
        off[i] = o;
        cur[i] = o;
    }
}

__global__ void scatter_kernel(const int* __restrict__ ei, int* __restrict__ cur,
                               int* __restrict__ elist) {
    int e = blockIdx.x * 256 + threadIdx.x;
    if (e < EE) {
        int d = ei[EE + e];
        int p = atomicAdd(&cur[d], 1);
        elist[p] = e;
    }
}

// ---------------------------------------------------------------------------
// fused per-node attention, persistent waves.
// Restructured vs previous version:
//  * K/V gathered as MFMA-A-layout fragments: lane(quad,l16) reads row sid[l16]
//    bytes [kk*64+quad*16,+16) -> one dwordx4 = 16 rows x one full 64B line.
//  * e (edge projection) is transposed edge-major via LDS in *f32*, one 64-col
//    head-half at a time (reuses the edge_attr scratch; no extra LDS, no bf16
//    requantization of e).
//  * alpha = q.(k+e): lane-local over 32 cols, reduced with 2 shfl_xor (m=16,32).
//  * out  += ex*(v+e): lane-local accumulator accA[4][8], reduced once per node.
//  * software pipeline: (eid,sid,lu,tt) descriptors for the next tile / next
//    node are loaded during the current tile's compute; off[] for node+stride
//    issues at node top.
// ---------------------------------------------------------------------------
__global__ __launch_bounds__(256, 3) void attn_kernel(
        const unsigned short* __restrict__ Qb, const unsigned short* __restrict__ Kb,
        const unsigned short* __restrict__ Vb, const unsigned short* __restrict__ Sb,
        const unsigned short* __restrict__ Wet, const float* __restrict__ be,
        const float* __restrict__ wt,  const float* __restrict__ bt,
        const float* __restrict__ lu,  const float* __restrict__ tt,
        const float* __restrict__ msg, const int* __restrict__ ei,
        const int* __restrict__ off, const int* __restrict__ elist,
        float* __restrict__ outp) {
    __shared__ unsigned short Wl[128][104];   // W_e^T, pitch 104 (26624 B)
    __shared__ float scrf[4][16][68];         // per-wave scratch, row pitch 272 B:
                                              //   bf16 view: edge_attr [16][96+]
                                              //   f32 view:  e half-tile [16][64+]
    const int tid = threadIdx.x;
    {   // stage W_e^T once per block: 2 threads per row, 48 shorts each
        int r = tid >> 1, half = tid & 1;
        const uint4* s = (const uint4*)(Wet + r * 96 + half * 48);
        uint4* d = (uint4*)&Wl[r][half * 48];
#pragma unroll
        for (int i = 0; i < 6; i++) d[i] = s[i];
    }
    __syncthreads();
    const int wave = tid >> 6, lane = tid & 63, quad = lane >> 4, l16 = lane & 15;
    const int er = lane >> 2, part = lane & 3;
    float q_be[8], wtv[8], btv[8];
#pragma unroll
    for (int nf = 0; nf < 8; nf++) q_be[nf] = be[l16 + nf * 16];
#pragma unroll
    for (int j = 0; j < 8; j++) { wtv[j] = wt[part * 8 + j]; btv[j] = bt[part * 8 + j]; }

    int node = blockIdx.x * 4 + wave;
    // prefetch CSR range of the first node, then its tile-0 edge descriptors
    int pf_e0 = 0, pf_dg = 0;
    if (node < NN) { pf_e0 = off[node]; pf_dg = off[node + 1] - pf_e0; }
    int c_eid = -1, c_sid = 0; float c_lu = 0.f, c_tt = 0.f;
    {
        int c0 = pf_dg < 16 ? pf_dg : 16;
        if (er < c0) { c_eid = elist[pf_e0 + er]; c_sid = ei[c_eid];
                       c_lu = lu[c_sid]; c_tt = tt[c_eid]; }
    }
    for (; node < NN; node += ATTN_WAVES) {
        const int e0 = pf_e0, dg = pf_dg;
        {   // issue next node's CSR range load now (used by the last tile below)
            int nn = node + ATTN_WAVES;
            if (nn < NN) { pf_e0 = off[nn]; pf_dg = off[nn + 1] - pf_e0; }
            else { pf_e0 = 0; pf_dg = 0; }
        }
        // q fragments, A-layout cols kk*32+quad*8..+8 (broadcast loads)
        u16x8 qf[4];
#pragma unroll
        for (int kk = 0; kk < 4; kk++)
            qf[kk] = *(const u16x8*)(Qb + (size_t)node * 128 + kk * 32 + quad * 8);
        float accA[4][8];
#pragma unroll
        for (int kk = 0; kk < 4; kk++)
#pragma unroll
            for (int j = 0; j < 8; j++) accA[kk][j] = 0.f;
        float l0 = 0.f, l1 = 0.f;

        for (int tb = 0; tb < dg; tb += 16) {
            int cnt = dg - tb; if (cnt > 16) cnt = 16;
            // previous tile's scratch reads retired before overwrite
            __asm__ volatile("s_waitcnt lgkmcnt(0)" ::: "memory");
            // broadcast per-edge src ids across the wave (lane l16 <- lane 4*l16)
            int sidv = __shfl(c_sid, l16 << 2, 64);
            // K/V gathers, A-fragment layout: 16 rows x one full 64B line / instr
            u16x8 kf[4], vf[4];
            {
                const unsigned short* kp = Kb + (size_t)sidv * 128 + quad * 8;
                const unsigned short* vp = Vb + (size_t)sidv * 128 + quad * 8;
#pragma unroll
                for (int kk = 0; kk < 4; kk++) {
                    kf[kk] = *(const u16x8*)(kp + kk * 32);
                    vf[kk] = *(const u16x8*)(vp + kk * 32);
                }
            }
            // msg gather (fp32) -> scratch cols 32..95 (bf16 view)
            unsigned short* earow = (unsigned short*)&scrf[wave][er][0];
            float mv[16];
#pragma unroll
            for (int i = 0; i < 16; i++) mv[i] = 0.f;
            if (c_eid >= 0) {
                const float4* mp = (const float4*)(msg + (size_t)c_eid * 64 + part * 16);
#pragma unroll
                for (int i = 0; i < 4; i++) *(float4*)&mv[i * 4] = mp[i];
            }
            // next-tile / next-node descriptor prefetch, step 1 (elist)
            bool more = (tb + 16 < dg);
            int nbase = more ? (e0 + tb + 16) : pf_e0;
            int ndg   = more ? (dg - tb - 16) : pf_dg;
            int ncnt  = ndg < 16 ? ndg : 16;
            int n_eid = -1, n_sid = 0; float n_lu = 0.f, n_tt = 0.f;
            if (er < ncnt) n_eid = elist[nbase + er];
            // pack msg + time encoding into edge_attr scratch
#pragma unroll
            for (int c = 0; c < 2; c++) {
                u16x8 h;
#pragma unroll
                for (int j = 0; j < 8; j++) h[j] = f2b(mv[c * 8 + j]);
                *(u16x8*)&earow[32 + part * 16 + c * 8] = h;
            }
            u16x8 tv = {0, 0, 0, 0, 0, 0, 0, 0};
            if (c_eid >= 0) {
                float rel = c_lu - c_tt;
#pragma unroll
                for (int j = 0; j < 8; j++) tv[j] = f2b(__cosf(rel * wtv[j] + btv[j]));
            }
            *(u16x8*)&earow[part * 8] = tv;
            if (er < ncnt) n_sid = ei[n_eid];          // prefetch step 2
            __asm__ volatile("s_waitcnt lgkmcnt(0)" ::: "memory");
            __builtin_amdgcn_sched_barrier(0);
            // e projection (acc init = b_e): D[edge=quad*4+r][col=l16+nf*16]
            f32x4 acc8[8];
#pragma unroll
            for (int nf = 0; nf < 8; nf++) {
                float b = q_be[nf];
                acc8[nf] = (f32x4){b, b, b, b};
            }
            const unsigned short* ea16 = (const unsigned short*)&scrf[wave][l16][0];
#pragma unroll
            for (int kk = 0; kk < 3; kk++) {
                bf16x8 af = *(const bf16x8*)&ea16[kk * 32 + quad * 8];
#pragma unroll
                for (int nf = 0; nf < 8; nf++) {
                    bf16x8 bg = *(const bf16x8*)&Wl[l16 + nf * 16][kk * 32 + quad * 8];
                    acc8[nf] = __builtin_amdgcn_mfma_f32_16x16x32_bf16(af, bg, acc8[nf], 0, 0, 0);
                }
            }
            if (er < ncnt) { n_lu = lu[n_sid]; n_tt = tt[n_eid]; }   // prefetch step 3
            float ex0, ex1;
            // ---- half 0: head 0 (cols 0..63), e transposed through LDS in f32 ----
            // (wave-wide: all edge_attr ds_reads retired before MFMA issued)
            __asm__ volatile("" ::: "memory");
#pragma unroll
            for (int nf = 0; nf < 4; nf++)
#pragma unroll
                for (int r = 0; r < 4; r++)
                    scrf[wave][quad * 4 + r][l16 + nf * 16] = acc8[nf][r];
            __asm__ volatile("s_waitcnt lgkmcnt(0)" ::: "memory");
            __builtin_amdgcn_sched_barrier(0);
            float ef0[16];
#pragma unroll
            for (int kk = 0; kk < 2; kk++) {
                *(float4*)&ef0[kk * 8 + 0] = *(const float4*)&scrf[wave][l16][kk * 32 + quad * 8];
                *(float4*)&ef0[kk * 8 + 4] = *(const float4*)&scrf[wave][l16][kk * 32 + quad * 8 + 4];
            }
            {
                float p0 = 0.f;
#pragma unroll
                for (int kk = 0; kk < 2; kk++)
#pragma unroll
                    for (int j = 0; j < 8; j++)
                        p0 += b2f(qf[kk][j]) * (b2f(kf[kk][j]) + ef0[kk * 8 + j]);
                p0 += __shfl_xor(p0, 16, 64);
                p0 += __shfl_xor(p0, 32, 64);
                ex0 = (l16 < cnt) ? __expf(p0 * 0.125f) : 0.f;
                l0 += ex0;
#pragma unroll
                for (int kk = 0; kk < 2; kk++)
#pragma unroll
                    for (int j = 0; j < 8; j++)
                        accA[kk][j] += ex0 * (b2f(vf[kk][j]) + ef0[kk * 8 + j]);
            }
            // ---- half 1: head 1 (cols 64..127) ----
            __asm__ volatile("s_waitcnt lgkmcnt(0)" ::: "memory");
#pragma unroll
            for (int nf = 0; nf < 4; nf++)
#pragma unroll
                for (int r = 0; r < 4; r++)
                    scrf[wave][quad * 4 + r][l16 + nf * 16] = acc8[4 + nf][r];
            __asm__ volatile("s_waitcnt lgkmcnt(0)" ::: "memory");
            __builtin_amdgcn_sched_barrier(0);
            float ef1[16];
#pragma unroll
            for (int kk = 0; kk < 2; kk++) {
                *(float4*)&ef1[kk * 8 + 0] = *(const float4*)&scrf[wave][l16][kk * 32 + quad * 8];
                *(float4*)&ef1[kk * 8 + 4] = *(const float4*)&scrf[wave][l16][kk * 32 + quad * 8 + 4];
            }
            {
                float p1 = 0.f;
#pragma unroll
                for (int kk = 0; kk < 2; kk++)
#pragma unroll
                    for (int j = 0; j < 8; j++)
                        p1 += b2f(qf[2 + kk][j]) * (b2f(kf[2 + kk][j]) + ef1[kk * 8 + j]);
                p1 += __shfl_xor(p1, 16, 64);
                p1 += __shfl_xor(p1, 32, 64);
                ex1 = (l16 < cnt) ? __expf(p1 * 0.125f) : 0.f;
                l1 += ex1;
#pragma unroll
                for (int kk = 0; kk < 2; kk++)
#pragma unroll
                    for (int j = 0; j < 8; j++)
                        accA[2 + kk][j] += ex1 * (b2f(vf[2 + kk][j]) + ef1[kk * 8 + j]);
            }
            // rotate descriptor
            c_eid = n_eid; c_sid = n_sid; c_lu = n_lu; c_tt = n_tt;
        }
        if (dg == 0) {   // keep the pipeline primed across empty nodes
            int c0 = pf_dg < 16 ? pf_dg : 16;
            c_eid = -1; c_sid = 0; c_lu = 0.f; c_tt = 0.f;
            if (er < c0) { c_eid = elist[pf_e0 + er]; c_sid = ei[c_eid];
                           c_lu = lu[c_sid]; c_tt = tt[c_eid]; }
        }
        // epilogue: reduce over the 16 edge-lanes inside each quad
#pragma unroll
        for (int m = 1; m < 16; m <<= 1) {
            l0 += __shfl_xor(l0, m, 64);
            l1 += __shfl_xor(l1, m, 64);
#pragma unroll
            for (int kk = 0; kk < 4; kk++)
#pragma unroll
                for (int j = 0; j < 8; j++)
                    accA[kk][j] += __shfl_xor(accA[kk][j], m, 64);
        }
        float inv0 = 1.f / (l0 + 1e-16f), inv1 = 1.f / (l1 + 1e-16f);
        if (l16 < 2) {   // 2 lanes per quad store 4 cols each per kk
#pragma unroll
            for (int kk = 0; kk < 4; kk++) {
                float inv = kk < 2 ? inv0 : inv1;
                int col = kk * 32 + quad * 8 + l16 * 4;
                // static-index selects (no runtime indexing -> no scratch)
                float a0 = l16 ? accA[kk][4] : accA[kk][0];
                float a1 = l16 ? accA[kk][5] : accA[kk][1];
                float a2 = l16 ? accA[kk][6] : accA[kk][2];
                float a3 = l16 ? accA[kk][7] : accA[kk][3];
                ushort4 sk = *(const ushort4*)(Sb + (size_t)node * 128 + col);
                float4 o;
                o.x = a0 * inv + b2f(sk.x);
                o.y = a1 * inv + b2f(sk.y);
                o.z = a2 * inv + b2f(sk.z);
                o.w = a3 * inv + b2f(sk.w);
                *(float4*)(outp + (size_t)node * 128 + col) = o;
            }
        }
    }
}

// ---------------------------------------------------------------------------
extern "C" void kernel_launch(void* const* d_in, const int* in_sizes, int n_in,
                              void* d_out, int out_size, void* d_ws, size_t ws_size,
                              hipStream_t stream) {
    (void)in_sizes; (void)n_in; (void)out_size; (void)ws_size;
    const float* x   = (const float*)d_in[0];
    const float* lu  = (const float*)d_in[1];
    const float* tt  = (const float*)d_in[2];
    const float* msg = (const float*)d_in[3];
    const int*   ei  = (const int*)d_in[4];
    const float* wt  = (const float*)d_in[5];
    const float* btm = (const float*)d_in[6];
    const float* Wq  = (const float*)d_in[7];
    const float* bq  = (const float*)d_in[8];
    const float* Wk  = (const float*)d_in[9];
    const float* bk  = (const float*)d_in[10];
    const float* Wv  = (const float*)d_in[11];
    const float* bv  = (const float*)d_in[12];
    const float* We  = (const float*)d_in[13];
    const float* be  = (const float*)d_in[14];
    const float* Ws  = (const float*)d_in[15];
    const float* bs  = (const float*)d_in[16];

    char* p = (char*)d_ws;
    auto alloc = [&](size_t bytes) -> char* {
        char* r = p; p += (bytes + 255) & ~(size_t)255; return r;
    };
    unsigned short* Qb   = (unsigned short*)alloc((size_t)NN * 128 * 2);
    unsigned short* Kb   = (unsigned short*)alloc((size_t)NN * 128 * 2);
    unsigned short* Vb   = (unsigned short*)alloc((size_t)NN * 128 * 2);
    unsigned short* Sb   = (unsigned short*)alloc((size_t)NN * 128 * 2);
    unsigned short* Wt   = (unsigned short*)alloc(512 * 128 * 2);
    unsigned short* Wet  = (unsigned short*)alloc(128 * 96 * 2);
    int* deg   = (int*)alloc(NN * 4);
    int* cur   = (int*)alloc(NN * 4);
    int* off   = (int*)alloc((NN + 1) * 4);
    int* elist = (int*)alloc((size_t)EE * 4);
    int* bsum  = (int*)alloc(SCAN_BLKS * 4);
    int* bpre  = (int*)alloc(SCAN_BLKS * 4);

    hipLaunchKernelGGL(prep_kernel, dim3(304), dim3(256), 0, stream,
                       Wq, Wk, Wv, Ws, We, Wt, Wet, deg);
    hipLaunchKernelGGL(node_gemm, dim3(782), dim3(256), 0, stream,
                       x, Wt, bq, bk, bv, bs, Qb, Kb, Vb, Sb);
    hipLaunchKernelGGL(deg_kernel, dim3((EE + 255) / 256), dim3(256), 0, stream, ei, deg);
    hipLaunchKernelGGL(scan1_kernel, dim3(SCAN_BLKS), dim3(256), 0, stream, deg, off, bsum);
    hipLaunchKernelGGL(scan2_kernel, dim3(1), dim3(256), 0, stream, bsum, bpre, off);
    hipLaunchKernelGGL(scan3_kernel, dim3(SCAN_BLKS), dim3(256), 0, stream, off, bpre, cur);
    hipLaunchKernelGGL(scatter_kernel, dim3((EE + 255) / 256), dim3(256), 0, stream,
                       ei, cur, elist);
    hipLaunchKernelGGL(attn_kernel, dim3(ATTN_BLOCKS), dim3(256), 0, stream,
                       Qb, Kb, Vb, Sb, Wet, be, wt, btm, lu, tt, msg, ei, off, elist,
                       (float*)d_out);
}

// Round 2
// 706.164 us; speedup vs baseline: 1.1141x; 1.1141x over previous
//
#include <hip/hip_runtime.h>

#define NN 50000
#define EE 800000
#define ATTN_BLOCKS 768          // 3 blocks/CU x 256 CUs (LDS-capped at 3)
#define ATTN_WAVES (ATTN_BLOCKS * 4)

using bf16x8 = __attribute__((ext_vector_type(8))) short;
using f32x4  = __attribute__((ext_vector_type(4))) float;
using u16x8  = __attribute__((ext_vector_type(8))) unsigned short;

__device__ __forceinline__ float b2f(unsigned short u) {
    return __uint_as_float(((unsigned)u) << 16);
}
__device__ __forceinline__ unsigned short f2b(float f) {
    unsigned u = __float_as_uint(f);
    u += 0x7FFF + ((u >> 16) & 1);   // round-to-nearest-even
    return (unsigned short)(u >> 16);
}

// ---------------------------------------------------------------------------
// prep: W_q|W_k|W_v|W_skip (fp32) -> Wt[512][128] bf16 (Wt[n][k] = W[k][n]),
//       W_e (fp32) -> Wet[128][96] bf16, and clear deg[]
// ---------------------------------------------------------------------------
__global__ void prep_kernel(const float* __restrict__ Wq,
                            const float* __restrict__ Wk,
                            const float* __restrict__ Wv,
                            const float* __restrict__ Ws,
                            const float* __restrict__ We,
                            unsigned short* __restrict__ Wt,
                            unsigned short* __restrict__ Wet,
                            int* __restrict__ deg) {
    int i = blockIdx.x * 256 + threadIdx.x;
    if (i < 512 * 128) {
        int n = i >> 7, k = i & 127;
        const float* W = (n < 128) ? Wq : (n < 256) ? Wk : (n < 384) ? Wv : Ws;
        Wt[i] = f2b(W[k * 128 + (n & 127)]);
    } else if (i < 512 * 128 + 128 * 96) {
        int j = i - 512 * 128;
        int n = j / 96, k = j - n * 96;
        Wet[j] = f2b(We[k * 128 + n]);
    }
    if (i < NN) deg[i] = 0;
}

// ---------------------------------------------------------------------------
// node projections: X[N,128]fp32 x Wt[512,128]bf16 -> Q,K,V,Skip (bf16)
// ---------------------------------------------------------------------------
__global__ __launch_bounds__(256) void node_gemm(
        const float* __restrict__ X, const unsigned short* __restrict__ Wt,
        const float* __restrict__ bq, const float* __restrict__ bk,
        const float* __restrict__ bv, const float* __restrict__ bs,
        unsigned short* __restrict__ Qb, unsigned short* __restrict__ Kb,
        unsigned short* __restrict__ Vb, unsigned short* __restrict__ Sb) {
    __shared__ unsigned short Al[64][136];   // pitch 136: 2-way bank aliasing (free)
    __shared__ unsigned short Bl[64][136];
    const int tid = threadIdx.x;
    const int m0 = blockIdx.x * 64;
    const int row = tid >> 2, seg = tid & 3;
    {
        int gr = m0 + row;
        float xv[32];
#pragma unroll
        for (int i = 0; i < 32; i++) xv[i] = 0.f;
        if (gr < NN) {
            const float4* s = (const float4*)(X + (size_t)gr * 128 + seg * 32);
#pragma unroll
            for (int i = 0; i < 8; i++) *(float4*)&xv[i * 4] = s[i];
        }
#pragma unroll
        for (int c = 0; c < 4; c++) {
            u16x8 h;
#pragma unroll
            for (int j = 0; j < 8; j++) h[j] = f2b(xv[c * 8 + j]);
            *(u16x8*)&Al[row][seg * 32 + c * 8] = h;
        }
    }
    const int wave = tid >> 6, lane = tid & 63, quad = lane >> 4, l16 = lane & 15;
    for (int n0t = 0; n0t < 8; n0t++) {
        __syncthreads();   // prior MFMA LDS reads done (and Al staged, iter 0)
        {
            const uint4* sb = (const uint4*)(Wt + (size_t)(n0t * 64 + row) * 128 + seg * 32);
            uint4 b0 = sb[0], b1 = sb[1], b2 = sb[2], b3 = sb[3];
            uint4* db = (uint4*)&Bl[row][seg * 32];
            db[0] = b0; db[1] = b1; db[2] = b2; db[3] = b3;
        }
        __syncthreads();
        f32x4 acc[4] = {{0.f,0.f,0.f,0.f},{0.f,0.f,0.f,0.f},{0.f,0.f,0.f,0.f},{0.f,0.f,0.f,0.f}};
#pragma unroll
        for (int kk = 0; kk < 4; kk++) {
            bf16x8 af = *(const bf16x8*)&Al[wave * 16 + l16][kk * 32 + quad * 8];
#pragma unroll
            for (int nf = 0; nf < 4; nf++) {
                bf16x8 bg = *(const bf16x8*)&Bl[nf * 16 + l16][kk * 32 + quad * 8];
                acc[nf] = __builtin_amdgcn_mfma_f32_16x16x32_bf16(af, bg, acc[nf], 0, 0, 0);
            }
        }
        const int sel = n0t >> 1;
        const float* bias    = sel == 0 ? bq : sel == 1 ? bk : sel == 2 ? bv : bs;
        unsigned short* outp = sel == 0 ? Qb : sel == 1 ? Kb : sel == 2 ? Vb : Sb;
#pragma unroll
        for (int nf = 0; nf < 4; nf++) {
            int col = (n0t & 1) * 64 + nf * 16 + l16;
            float bvl = bias[col];
#pragma unroll
            for (int r = 0; r < 4; r++) {
                int orow = m0 + wave * 16 + quad * 4 + r;   // C/D: row = quad*4+reg
                if (orow < NN) outp[(size_t)orow * 128 + col] = f2b(acc[nf][r] + bvl);
            }
        }
    }
}

// ---------------------------------------------------------------------------
// CSR build: deg histogram -> hierarchical exclusive scan -> scatter edge ids
// ---------------------------------------------------------------------------
__global__ void deg_kernel(const int* __restrict__ ei, int* __restrict__ deg) {
    int e = blockIdx.x * 256 + threadIdx.x;
    if (e < EE) atomicAdd(&deg[ei[EE + e]], 1);
}

#define SCAN_BLKS 196   // 196*256 = 50176 >= NN

__global__ __launch_bounds__(256) void scan1_kernel(const int* __restrict__ deg,
                                                    int* __restrict__ off,
                                                    int* __restrict__ bsum) {
    __shared__ int sm[256];
    int tid = threadIdx.x;
    int i = blockIdx.x * 256 + tid;
    int v = (i < NN) ? deg[i] : 0;
    sm[tid] = v;
    __syncthreads();
    for (int d = 1; d < 256; d <<= 1) {
        int t = (tid >= d) ? sm[tid - d] : 0;
        __syncthreads();
        sm[tid] += t;
        __syncthreads();
    }
    if (i < NN) off[i] = sm[tid] - v;           // block-local exclusive
    if (tid == 255) bsum[blockIdx.x] = sm[255]; // block total
}

__global__ __launch_bounds__(256) void scan2_kernel(int* __restrict__ bsum,
                                                    int* __restrict__ bpre,
                                                    int* __restrict__ off) {
    __shared__ int sm[256];
    int tid = threadIdx.x;
    int v = (tid < SCAN_BLKS) ? bsum[tid] : 0;
    sm[tid] = v;
    __syncthreads();
    for (int d = 1; d < 256; d <<= 1) {
        int t = (tid >= d) ? sm[tid - d] : 0;
        __syncthreads();
        sm[tid] += t;
        __syncthreads();
    }
    if (tid < SCAN_BLKS) bpre[tid] = sm[tid] - v;
    if (tid == 255) off[NN] = sm[255];          // = EE
}

__global__ __launch_bounds__(256) void scan3_kernel(int* __restrict__ off,
                                                    const int* __restrict__ bpre,
                                                    int* __restrict__ cur) {
    int i = blockIdx.x * 256 + threadIdx.x;
    if (i < NN) {
        int o = off[i] + bpre[blockIdx.x];
        off[i] = o;
        cur[i] = o;
    }
}

__global__ void scatter_kernel(const int* __restrict__ ei, int* __restrict__ cur,
                               int* __restrict__ elist) {
    int e = blockIdx.x * 256 + threadIdx.x;
    if (e < EE) {
        int d = ei[EE + e];
        int p = atomicAdd(&cur[d], 1);
        elist[p] = e;
    }
}

// ---------------------------------------------------------------------------
// fused per-node attention, persistent waves.
// Same pipeline as round 1 (A-layout K/V gathers, f32 LDS transpose of e,
// descriptor software pipeline) with the spill pressure removed:
//  * plain __launch_bounds__(256) — the (256,3) min-occupancy hint made the
//    allocator target ~84 VGPRs and spill accA/acc8 to scratch every tile
//    (WRITE_SIZE 25->238 MB was the tell).
//  * K/V fragments loaded per head-half (16 live regs instead of 32): head-0
//    issues right after sidv (hidden under msg-pack+MFMA), head-1 issues at
//    the start of half-0 compute (hidden under half-0 VALU).
// ---------------------------------------------------------------------------
__global__ __launch_bounds__(256) void attn_kernel(
        const unsigned short* __restrict__ Qb, const unsigned short* __restrict__ Kb,
        const unsigned short* __restrict__ Vb, const unsigned short* __restrict__ Sb,
        const unsigned short* __restrict__ Wet, const float* __restrict__ be,
        const float* __restrict__ wt,  const float* __restrict__ bt,
        const float* __restrict__ lu,  const float* __restrict__ tt,
        const float* __restrict__ msg, const int* __restrict__ ei,
        const int* __restrict__ off, const int* __restrict__ elist,
        float* __restrict__ outp) {
    __shared__ unsigned short Wl[128][104];   // W_e^T, pitch 104 (26624 B)
    __shared__ float scrf[4][16][68];         // per-wave scratch, row pitch 272 B:
                                              //   bf16 view: edge_attr [16][96+]
                                              //   f32 view:  e half-tile [16][64+]
    const int tid = threadIdx.x;
    {   // stage W_e^T once per block: 2 threads per row, 48 shorts each
        int r = tid >> 1, half = tid & 1;
        const uint4* s = (const uint4*)(Wet + r * 96 + half * 48);
        uint4* d = (uint4*)&Wl[r][half * 48];
#pragma unroll
        for (int i = 0; i < 6; i++) d[i] = s[i];
    }
    __syncthreads();
    const int wave = tid >> 6, lane = tid & 63, quad = lane >> 4, l16 = lane & 15;
    const int er = lane >> 2, part = lane & 3;
    float q_be[8], wtv[8], btv[8];
#pragma unroll
    for (int nf = 0; nf < 8; nf++) q_be[nf] = be[l16 + nf * 16];
#pragma unroll
    for (int j = 0; j < 8; j++) { wtv[j] = wt[part * 8 + j]; btv[j] = bt[part * 8 + j]; }

    int node = blockIdx.x * 4 + wave;
    // prefetch CSR range of the first node, then its tile-0 edge descriptors
    int pf_e0 = 0, pf_dg = 0;
    if (node < NN) { pf_e0 = off[node]; pf_dg = off[node + 1] - pf_e0; }
    int c_eid = -1, c_sid = 0; float c_lu = 0.f, c_tt = 0.f;
    {
        int c0 = pf_dg < 16 ? pf_dg : 16;
        if (er < c0) { c_eid = elist[pf_e0 + er]; c_sid = ei[c_eid];
                       c_lu = lu[c_sid]; c_tt = tt[c_eid]; }
    }
    for (; node < NN; node += ATTN_WAVES) {
        const int e0 = pf_e0, dg = pf_dg;
        {   // issue next node's CSR range load now (used by the last tile below)
            int nn = node + ATTN_WAVES;
            if (nn < NN) { pf_e0 = off[nn]; pf_dg = off[nn + 1] - pf_e0; }
            else { pf_e0 = 0; pf_dg = 0; }
        }
        // q fragments, A-layout cols kk*32+quad*8..+8 (broadcast loads)
        u16x8 qf[4];
#pragma unroll
        for (int kk = 0; kk < 4; kk++)
            qf[kk] = *(const u16x8*)(Qb + (size_t)node * 128 + kk * 32 + quad * 8);
        float accA[4][8];
#pragma unroll
        for (int kk = 0; kk < 4; kk++)
#pragma unroll
            for (int j = 0; j < 8; j++) accA[kk][j] = 0.f;
        float l0 = 0.f, l1 = 0.f;

        for (int tb = 0; tb < dg; tb += 16) {
            int cnt = dg - tb; if (cnt > 16) cnt = 16;
            // previous tile's scratch reads retired before overwrite
            __asm__ volatile("s_waitcnt lgkmcnt(0)" ::: "memory");
            // broadcast per-edge src ids across the wave (lane l16 <- lane 4*l16)
            int sidv = __shfl(c_sid, l16 << 2, 64);
            // K/V gathers, A-fragment layout: 16 rows x one full 64B line / instr.
            // head 0 only here (head 1 issues during half-0 compute).
            const unsigned short* kp = Kb + (size_t)sidv * 128 + quad * 8;
            const unsigned short* vp = Vb + (size_t)sidv * 128 + quad * 8;
            u16x8 kA0 = *(const u16x8*)(kp);
            u16x8 kA1 = *(const u16x8*)(kp + 32);
            u16x8 vA0 = *(const u16x8*)(vp);
            u16x8 vA1 = *(const u16x8*)(vp + 32);
            // msg gather (fp32) -> scratch cols 32..95 (bf16 view)
            unsigned short* earow = (unsigned short*)&scrf[wave][er][0];
            float mv[16];
#pragma unroll
            for (int i = 0; i < 16; i++) mv[i] = 0.f;
            if (c_eid >= 0) {
                const float4* mp = (const float4*)(msg + (size_t)c_eid * 64 + part * 16);
#pragma unroll
                for (int i = 0; i < 4; i++) *(float4*)&mv[i * 4] = mp[i];
            }
            // next-tile / next-node descriptor prefetch, step 1 (elist)
            bool more = (tb + 16 < dg);
            int nbase = more ? (e0 + tb + 16) : pf_e0;
            int ndg   = more ? (dg - tb - 16) : pf_dg;
            int ncnt  = ndg < 16 ? ndg : 16;
            int n_eid = -1, n_sid = 0; float n_lu = 0.f, n_tt = 0.f;
            if (er < ncnt) n_eid = elist[nbase + er];
            // pack msg + time encoding into edge_attr scratch
#pragma unroll
            for (int c = 0; c < 2; c++) {
                u16x8 h;
#pragma unroll
                for (int j = 0; j < 8; j++) h[j] = f2b(mv[c * 8 + j]);
                *(u16x8*)&earow[32 + part * 16 + c * 8] = h;
            }
            u16x8 tv = {0, 0, 0, 0, 0, 0, 0, 0};
            if (c_eid >= 0) {
                float rel = c_lu - c_tt;
#pragma unroll
                for (int j = 0; j < 8; j++) tv[j] = f2b(__cosf(rel * wtv[j] + btv[j]));
            }
            *(u16x8*)&earow[part * 8] = tv;
            if (er < ncnt) n_sid = ei[n_eid];          // prefetch step 2
            __asm__ volatile("s_waitcnt lgkmcnt(0)" ::: "memory");
            __builtin_amdgcn_sched_barrier(0);
            // e projection (acc init = b_e): D[edge=quad*4+r][col=l16+nf*16]
            f32x4 acc8[8];
#pragma unroll
            for (int nf = 0; nf < 8; nf++) {
                float b = q_be[nf];
                acc8[nf] = (f32x4){b, b, b, b};
            }
            const unsigned short* ea16 = (const unsigned short*)&scrf[wave][l16][0];
#pragma unroll
            for (int kk = 0; kk < 3; kk++) {
                bf16x8 af = *(const bf16x8*)&ea16[kk * 32 + quad * 8];
#pragma unroll
                for (int nf = 0; nf < 8; nf++) {
                    bf16x8 bg = *(const bf16x8*)&Wl[l16 + nf * 16][kk * 32 + quad * 8];
                    acc8[nf] = __builtin_amdgcn_mfma_f32_16x16x32_bf16(af, bg, acc8[nf], 0, 0, 0);
                }
            }
            if (er < ncnt) { n_lu = lu[n_sid]; n_tt = tt[n_eid]; }   // prefetch step 3
            float ex0, ex1;
            // ---- half 0: head 0 (cols 0..63), e transposed through LDS in f32 ----
            // (per-wave DS ordering: MFMA's ea reads precede these writes)
            __asm__ volatile("" ::: "memory");
#pragma unroll
            for (int nf = 0; nf < 4; nf++)
#pragma unroll
                for (int r = 0; r < 4; r++)
                    scrf[wave][quad * 4 + r][l16 + nf * 16] = acc8[nf][r];
            __asm__ volatile("s_waitcnt lgkmcnt(0)" ::: "memory");
            __builtin_amdgcn_sched_barrier(0);
            float ef0[16];
#pragma unroll
            for (int kk = 0; kk < 2; kk++) {
                *(float4*)&ef0[kk * 8 + 0] = *(const float4*)&scrf[wave][l16][kk * 32 + quad * 8];
                *(float4*)&ef0[kk * 8 + 4] = *(const float4*)&scrf[wave][l16][kk * 32 + quad * 8 + 4];
            }
            // issue head-1 K/V gathers now (consumed in half 1)
            u16x8 kB0 = *(const u16x8*)(kp + 64);
            u16x8 kB1 = *(const u16x8*)(kp + 96);
            u16x8 vB0 = *(const u16x8*)(vp + 64);
            u16x8 vB1 = *(const u16x8*)(vp + 96);
            {
                float p0 = 0.f;
#pragma unroll
                for (int j = 0; j < 8; j++)
                    p0 += b2f(qf[0][j]) * (b2f(kA0[j]) + ef0[j]);
#pragma unroll
                for (int j = 0; j < 8; j++)
                    p0 += b2f(qf[1][j]) * (b2f(kA1[j]) + ef0[8 + j]);
                p0 += __shfl_xor(p0, 16, 64);
                p0 += __shfl_xor(p0, 32, 64);
                ex0 = (l16 < cnt) ? __expf(p0 * 0.125f) : 0.f;
                l0 += ex0;
#pragma unroll
                for (int j = 0; j < 8; j++)
                    accA[0][j] += ex0 * (b2f(vA0[j]) + ef0[j]);
#pragma unroll
                for (int j = 0; j < 8; j++)
                    accA[1][j] += ex0 * (b2f(vA1[j]) + ef0[8 + j]);
            }
            // ---- half 1: head 1 (cols 64..127) ----
            __asm__ volatile("s_waitcnt lgkmcnt(0)" ::: "memory");
#pragma unroll
            for (int nf = 0; nf < 4; nf++)
#pragma unroll
                for (int r = 0; r < 4; r++)
                    scrf[wave][quad * 4 + r][l16 + nf * 16] = acc8[4 + nf][r];
            __asm__ volatile("s_waitcnt lgkmcnt(0)" ::: "memory");
            __builtin_amdgcn_sched_barrier(0);
            float ef1[16];
#pragma unroll
            for (int kk = 0; kk < 2; kk++) {
                *(float4*)&ef1[kk * 8 + 0] = *(const float4*)&scrf[wave][l16][kk * 32 + quad * 8];
                *(float4*)&ef1[kk * 8 + 4] = *(const float4*)&scrf[wave][l16][kk * 32 + quad * 8 + 4];
            }
            {
                float p1 = 0.f;
#pragma unroll
                for (int j = 0; j < 8; j++)
                    p1 += b2f(qf[2][j]) * (b2f(kB0[j]) + ef1[j]);
#pragma unroll
                for (int j = 0; j < 8; j++)
                    p1 += b2f(qf[3][j]) * (b2f(kB1[j]) + ef1[8 + j]);
                p1 += __shfl_xor(p1, 16, 64);
                p1 += __shfl_xor(p1, 32, 64);
                ex1 = (l16 < cnt) ? __expf(p1 * 0.125f) : 0.f;
                l1 += ex1;
#pragma unroll
                for (int j = 0; j < 8; j++)
                    accA[2][j] += ex1 * (b2f(vB0[j]) + ef1[j]);
#pragma unroll
                for (int j = 0; j < 8; j++)
                    accA[3][j] += ex1 * (b2f(vB1[j]) + ef1[8 + j]);
            }
            // rotate descriptor
            c_eid = n_eid; c_sid = n_sid; c_lu = n_lu; c_tt = n_tt;
        }
        if (dg == 0) {   // keep the pipeline primed across empty nodes
            int c0 = pf_dg < 16 ? pf_dg : 16;
            c_eid = -1; c_sid = 0; c_lu = 0.f; c_tt = 0.f;
            if (er < c0) { c_eid = elist[pf_e0 + er]; c_sid = ei[c_eid];
                           c_lu = lu[c_sid]; c_tt = tt[c_eid]; }
        }
        // epilogue: reduce over the 16 edge-lanes inside each quad
#pragma unroll
        for (int m = 1; m < 16; m <<= 1) {
            l0 += __shfl_xor(l0, m, 64);
            l1 += __shfl_xor(l1, m, 64);
#pragma unroll
            for (int kk = 0; kk < 4; kk++)
#pragma unroll
                for (int j = 0; j < 8; j++)
                    accA[kk][j] += __shfl_xor(accA[kk][j], m, 64);
        }
        float inv0 = 1.f / (l0 + 1e-16f), inv1 = 1.f / (l1 + 1e-16f);
        if (l16 < 2) {   // 2 lanes per quad store 4 cols each per kk
#pragma unroll
            for (int kk = 0; kk < 4; kk++) {
                float inv = kk < 2 ? inv0 : inv1;
                int col = kk * 32 + quad * 8 + l16 * 4;
                // static-index selects (no runtime indexing -> no scratch)
                float a0 = l16 ? accA[kk][4] : accA[kk][0];
                float a1 = l16 ? accA[kk][5] : accA[kk][1];
                float a2 = l16 ? accA[kk][6] : accA[kk][2];
                float a3 = l16 ? accA[kk][7] : accA[kk][3];
                ushort4 sk = *(const ushort4*)(Sb + (size_t)node * 128 + col);
                float4 o;
                o.x = a0 * inv + b2f(sk.x);
                o.y = a1 * inv + b2f(sk.y);
                o.z = a2 * inv + b2f(sk.z);
                o.w = a3 * inv + b2f(sk.w);
                *(float4*)(outp + (size_t)node * 128 + col) = o;
            }
        }
    }
}

// ---------------------------------------------------------------------------
extern "C" void kernel_launch(void* const* d_in, const int* in_sizes, int n_in,
                              void* d_out, int out_size, void* d_ws, size_t ws_size,
                              hipStream_t stream) {
    (void)in_sizes; (void)n_in; (void)out_size; (void)ws_size;
    const float* x   = (const float*)d_in[0];
    const float* lu  = (const float*)d_in[1];
    const float* tt  = (const float*)d_in[2];
    const float* msg = (const float*)d_in[3];
    const int*   ei  = (const int*)d_in[4];
    const float* wt  = (const float*)d_in[5];
    const float* btm = (const float*)d_in[6];
    const float* Wq  = (const float*)d_in[7];
    const float* bq  = (const float*)d_in[8];
    const float* Wk  = (const float*)d_in[9];
    const float* bk  = (const float*)d_in[10];
    const float* Wv  = (const float*)d_in[11];
    const float* bv  = (const float*)d_in[12];
    const float* We  = (const float*)d_in[13];
    const float* be  = (const float*)d_in[14];
    const float* Ws  = (const float*)d_in[15];
    const float* bs  = (const float*)d_in[16];

    char* p = (char*)d_ws;
    auto alloc = [&](size_t bytes) -> char* {
        char* r = p; p += (bytes + 255) & ~(size_t)255; return r;
    };
    unsigned short* Qb   = (unsigned short*)alloc((size_t)NN * 128 * 2);
    unsigned short* Kb   = (unsigned short*)alloc((size_t)NN * 128 * 2);
    unsigned short* Vb   = (unsigned short*)alloc((size_t)NN * 128 * 2);
    unsigned short* Sb   = (unsigned short*)alloc((size_t)NN * 128 * 2);
    unsigned short* Wt   = (unsigned short*)alloc(512 * 128 * 2);
    unsigned short* Wet  = (unsigned short*)alloc(128 * 96 * 2);
    int* deg   = (int*)alloc(NN * 4);
    int* cur   = (int*)alloc(NN * 4);
    int* off   = (int*)alloc((NN + 1) * 4);
    int* elist = (int*)alloc((size_t)EE * 4);
    int* bsum  = (int*)alloc(SCAN_BLKS * 4);
    int* bpre  = (int*)alloc(SCAN_BLKS * 4);

    hipLaunchKernelGGL(prep_kernel, dim3(304), dim3(256), 0, stream,
                       Wq, Wk, Wv, Ws, We, Wt, Wet, deg);
    hipLaunchKernelGGL(node_gemm, dim3(782), dim3(256), 0, stream,
                       x, Wt, bq, bk, bv, bs, Qb, Kb, Vb, Sb);
    hipLaunchKernelGGL(deg_kernel, dim3((EE + 255) / 256), dim3(256), 0, stream, ei, deg);
    hipLaunchKernelGGL(scan1_kernel, dim3(SCAN_BLKS), dim3(256), 0, stream, deg, off, bsum);
    hipLaunchKernelGGL(scan2_kernel, dim3(1), dim3(256), 0, stream, bsum, bpre, off);
    hipLaunchKernelGGL(scan3_kernel, dim3(SCAN_BLKS), dim3(256), 0, stream, off, bpre, cur);
    hipLaunchKernelGGL(scatter_kernel, dim3((EE + 255) / 256), dim3(256), 0, stream,
                       ei, cur, elist);
    hipLaunchKernelGGL(attn_kernel, dim3(ATTN_BLOCKS), dim3(256), 0, stream,
                       Qb, Kb, Vb, Sb, Wet, be, wt, btm, lu, tt, msg, ei, off, elist,
                       (float*)d_out);
}